// Round 4
// baseline (534.094 us; speedup 1.0000x reference)
//
#include <hip/hip_runtime.h>

#define NTH 256
#define B_TOTAL 32768

struct Ptrs { const float* p[44]; };

// input indices
enum : int {
  I_X = 0,
  I_WH0 = 1, I_WY0 = 2, I_WYU0 = 3, I_WU0 = 4,
  I_WH1 = 5, I_WZ1 = 6, I_WZU1 = 7, I_WY1 = 8, I_WYU1 = 9, I_WU1 = 10,
  I_WH2 = 11, I_WZ2 = 12, I_WZU2 = 13, I_WY2 = 14, I_WYU2 = 15, I_WU2 = 16,
  I_WZO = 17, I_WZUO = 18, I_WYO = 19, I_WYUO = 20, I_WUO = 21,
  I_BY0 = 22, I_BH0 = 23, I_B0 = 24, I_BH1 = 25, I_BY1 = 26, I_BZ1 = 27, I_B1 = 28,
  I_BH2 = 29, I_BZ2 = 30, I_BY2 = 31, I_B2 = 32, I_BZO = 33, I_BYO = 34, I_BOUT = 35,
  I_FC1 = 36, I_FC1B = 37, I_FC2 = 38, I_FC2B = 39, I_FC3 = 40, I_FC3B = 41,
  I_FC4 = 42, I_FC4B = 43
};

// jet: c[0]=v, c[1..3]=dy, c[4..6]=dq, c[7..12]=d2yy sym {00,01,02,11,12,22},
// c[13..21]=d2ydq [a*3+b]
struct V22 { float c[22]; };
struct V4q { float c[4]; };

__device__ __forceinline__ float spf(float x) {
  return fmaxf(x, 0.0f) + __logf(1.0f + __expf(-fabsf(x)));
}
__device__ __forceinline__ float sigf(float x) {
  return __fdividef(1.0f, 1.0f + __expf(-x));
}

__device__ __forceinline__ V22 spchain22(const V22& A) {
  V22 Z;
  float s = sigf(A.c[0]);
  float d = s * (1.0f - s);
  Z.c[0] = spf(A.c[0]);
#pragma unroll
  for (int a = 0; a < 3; ++a) Z.c[1 + a] = s * A.c[1 + a];
#pragma unroll
  for (int b = 0; b < 3; ++b) Z.c[4 + b] = s * A.c[4 + b];
  const int pa[6] = {0, 0, 0, 1, 1, 2}, pb[6] = {0, 1, 2, 1, 2, 2};
#pragma unroll
  for (int t = 0; t < 6; ++t)
    Z.c[7 + t] = s * A.c[7 + t] + d * A.c[1 + pa[t]] * A.c[1 + pb[t]];
#pragma unroll
  for (int a = 0; a < 3; ++a)
#pragma unroll
    for (int b = 0; b < 3; ++b)
      Z.c[13 + a * 3 + b] = s * A.c[13 + a * 3 + b] + d * A.c[1 + a] * A.c[4 + b];
  return Z;
}

__device__ __forceinline__ V4q sp4(const V4q& h) {
  V4q u;
  float ss = sigf(h.c[0]);
  u.c[0] = spf(h.c[0]);
  u.c[1] = ss * h.c[1];
  u.c[2] = ss * h.c[2];
  u.c[3] = ss * h.c[3];
  return u;
}

// fused: P = Z * S (product-rule jet), streamed straight to LDS row as float4s
__device__ __forceinline__ void stageProd(float* row, const V22& Z, const V4q& S) {
  float z0 = Z.c[0], s0 = S.c[0];
  *(float4*)(row + 0) = make_float4(z0 * s0, s0 * Z.c[1], s0 * Z.c[2], s0 * Z.c[3]);
  *(float4*)(row + 4) = make_float4(z0 * S.c[1] + s0 * Z.c[4],
                                    z0 * S.c[2] + s0 * Z.c[5],
                                    z0 * S.c[3] + s0 * Z.c[6],
                                    s0 * Z.c[7]);
  *(float4*)(row + 8)  = make_float4(s0 * Z.c[8], s0 * Z.c[9], s0 * Z.c[10], s0 * Z.c[11]);
  *(float4*)(row + 12) = make_float4(s0 * Z.c[12],
                                     s0 * Z.c[13] + Z.c[1] * S.c[1],
                                     s0 * Z.c[14] + Z.c[1] * S.c[2],
                                     s0 * Z.c[15] + Z.c[1] * S.c[3]);
  *(float4*)(row + 16) = make_float4(s0 * Z.c[16] + Z.c[2] * S.c[1],
                                     s0 * Z.c[17] + Z.c[2] * S.c[2],
                                     s0 * Z.c[18] + Z.c[2] * S.c[3],
                                     s0 * Z.c[19] + Z.c[3] * S.c[1]);
  *(float4*)(row + 20) = make_float4(s0 * Z.c[20] + Z.c[3] * S.c[2],
                                     s0 * Z.c[21] + Z.c[3] * S.c[3], 0.0f, 0.0f);
}

// full-register product (only used for the final reduction stage)
__device__ __forceinline__ V22 prodZS(const V22& Z, const V4q& S) {
  V22 P;
  P.c[0] = Z.c[0] * S.c[0];
#pragma unroll
  for (int a = 0; a < 3; ++a) P.c[1 + a] = S.c[0] * Z.c[1 + a];
#pragma unroll
  for (int b = 0; b < 3; ++b) P.c[4 + b] = Z.c[0] * S.c[1 + b] + S.c[0] * Z.c[4 + b];
#pragma unroll
  for (int t = 0; t < 6; ++t) P.c[7 + t] = S.c[0] * Z.c[7 + t];
#pragma unroll
  for (int a = 0; a < 3; ++a)
#pragma unroll
    for (int b = 0; b < 3; ++b)
      P.c[13 + a * 3 + b] = S.c[0] * Z.c[13 + a * 3 + b] + Z.c[1 + a] * S.c[1 + b];
  return P;
}

// half-jet matvec passes: acc.c[0..11] / acc.c[12..21] += sum_i p[i][k]*relu(W[i*32+j])
template <bool RELU>
__device__ __forceinline__ void mv22gA(const float* __restrict__ W, int j,
                                       const float* ps, V22& acc) {
#pragma unroll 4
  for (int i = 0; i < 32; ++i) {
    float w = W[i * 32 + j];
    if (RELU) w = fmaxf(w, 0.0f);
    const float* r = ps + i * 28;
    float4 r0 = *(const float4*)(r + 0);
    float4 r1 = *(const float4*)(r + 4);
    float4 r2 = *(const float4*)(r + 8);
    acc.c[0] += r0.x * w;  acc.c[1] += r0.y * w;  acc.c[2] += r0.z * w;  acc.c[3] += r0.w * w;
    acc.c[4] += r1.x * w;  acc.c[5] += r1.y * w;  acc.c[6] += r1.z * w;  acc.c[7] += r1.w * w;
    acc.c[8] += r2.x * w;  acc.c[9] += r2.y * w;  acc.c[10] += r2.z * w; acc.c[11] += r2.w * w;
  }
}
template <bool RELU>
__device__ __forceinline__ void mv22gB(const float* __restrict__ W, int j,
                                       const float* ps, V22& acc) {
#pragma unroll 4
  for (int i = 0; i < 32; ++i) {
    float w = W[i * 32 + j];
    if (RELU) w = fmaxf(w, 0.0f);
    const float* r = ps + i * 28;
    float4 r3 = *(const float4*)(r + 12);
    float4 r4 = *(const float4*)(r + 16);
    float4 r5 = *(const float4*)(r + 20);
    acc.c[12] += r3.x * w; acc.c[13] += r3.y * w; acc.c[14] += r3.z * w; acc.c[15] += r3.w * w;
    acc.c[16] += r4.x * w; acc.c[17] += r4.y * w; acc.c[18] += r4.z * w; acc.c[19] += r4.w * w;
    acc.c[20] += r5.x * w; acc.c[21] += r5.y * w;
  }
}

// u-consumers, split into low-pressure passes
__device__ __forceinline__ void stageU_hs(const float* __restrict__ Wh,
                                          const float* __restrict__ Wzu, int j,
                                          const float* us, V4q& h, V4q& s) {
#pragma unroll 4
  for (int i = 0; i < 32; ++i) {
    float4 u = *(const float4*)(us + i * 4);
    float wh = Wh[i * 32 + j], wz = Wzu[i * 32 + j];
    h.c[0] += u.x * wh; h.c[1] += u.y * wh; h.c[2] += u.z * wh; h.c[3] += u.w * wh;
    s.c[0] += u.x * wz; s.c[1] += u.y * wz; s.c[2] += u.z * wz; s.c[3] += u.w * wz;
  }
}
__device__ __forceinline__ void stageU_wt(const float* __restrict__ Wu,
                                          const float* __restrict__ Wyu, int j,
                                          const float* us, V4q& w,
                                          V4q& t0, V4q& t1, V4q& t2) {
#pragma unroll 4
  for (int i = 0; i < 32; ++i) {
    float4 u = *(const float4*)(us + i * 4);
    float wu = Wu[i * 32 + j];
    w.c[0] += u.x * wu; w.c[1] += u.y * wu; w.c[2] += u.z * wu; w.c[3] += u.w * wu;
    float wy0 = Wyu[i * 3 + 0], wy1 = Wyu[i * 3 + 1], wy2 = Wyu[i * 3 + 2];
    t0.c[0] += u.x * wy0; t0.c[1] += u.y * wy0; t0.c[2] += u.z * wy0; t0.c[3] += u.w * wy0;
    t1.c[0] += u.x * wy1; t1.c[1] += u.y * wy1; t1.c[2] += u.z * wy1; t1.c[3] += u.w * wy1;
    t2.c[0] += u.x * wy2; t2.c[1] += u.y * wy2; t2.c[2] += u.z * wy2; t2.c[3] += u.w * wy2;
  }
}

// local (non-matvec) terms of a pre-activation: A = w + (y*t)@Wy, Wy (3,32) global
__device__ __forceinline__ void buildA(const float* __restrict__ Wy, int j, float y0, float y1,
                                       float y2, const V4q& w, const V4q& t0, const V4q& t1,
                                       const V4q& t2, V22& A) {
  float wy0 = Wy[j], wy1 = Wy[32 + j], wy2 = Wy[64 + j];
  A.c[0] = w.c[0] + y0 * t0.c[0] * wy0 + y1 * t1.c[0] * wy1 + y2 * t2.c[0] * wy2;
  A.c[1] = t0.c[0] * wy0; A.c[2] = t1.c[0] * wy1; A.c[3] = t2.c[0] * wy2;
#pragma unroll
  for (int b = 0; b < 3; ++b)
    A.c[4 + b] = w.c[1 + b] + y0 * t0.c[1 + b] * wy0 + y1 * t1.c[1 + b] * wy1 +
                 y2 * t2.c[1 + b] * wy2;
#pragma unroll
  for (int t6 = 0; t6 < 6; ++t6) A.c[7 + t6] = 0.0f;
#pragma unroll
  for (int b = 0; b < 3; ++b) {
    A.c[13 + 0 * 3 + b] = t0.c[1 + b] * wy0;
    A.c[13 + 1 * 3 + b] = t1.c[1 + b] * wy1;
    A.c[13 + 2 * 3 + b] = t2.c[1 + b] * wy2;
  }
}

// out = bias + V @ Wrow; fully static indexing
__device__ __forceinline__ V4q vmat(const float* __restrict__ Wrow, const float* us, float bias) {
  V4q a = {{bias, 0.f, 0.f, 0.f}};
#pragma unroll
  for (int r = 0; r < 8; ++r) {
    float4 w4 = *(const float4*)(Wrow + r * 4);
    float4 u0 = *(const float4*)(us + (r * 4 + 0) * 4);
    float4 u1 = *(const float4*)(us + (r * 4 + 1) * 4);
    float4 u2 = *(const float4*)(us + (r * 4 + 2) * 4);
    float4 u3 = *(const float4*)(us + (r * 4 + 3) * 4);
    a.c[0] += u0.x * w4.x + u1.x * w4.y + u2.x * w4.z + u3.x * w4.w;
    a.c[1] += u0.y * w4.x + u1.y * w4.y + u2.y * w4.z + u3.y * w4.w;
    a.c[2] += u0.z * w4.x + u1.z * w4.y + u2.z * w4.z + u3.z * w4.w;
    a.c[3] += u0.w * w4.x + u1.w * w4.y + u2.w * w4.z + u3.w * w4.w;
  }
  return a;
}

__global__ __launch_bounds__(NTH) void lnn_step_kernel(Ptrs P, float* __restrict__ out) {
  // LDS: jet staging only (32 KiB). Reads are same-row broadcasts (conflict-free).
  __shared__ float pstage[4][2][32][28];  // 28 KiB
  __shared__ float ustage[4][2][32][4];   // 4 KiB

  const int tid = threadIdx.x;
  const int j = tid & 31;
  const int half = (tid >> 5) & 1;
  const int wv = tid >> 6;
  const int sample = blockIdx.x * 8 + (tid >> 5);

  float* prow = &pstage[wv][half][0][0];
  float* urow = &ustage[wv][half][0][0];

  const float* X = P.p[I_X] + sample * 6;
  const float q0 = X[0], q1 = X[1], q2 = X[2];
  const float y0 = X[3], y1 = X[4], y2 = X[5];

  // ---------------- V chain first; keep only dV/dq ----------------
  float Vg0, Vg1, Vg2;
  {
    const float* fc1 = P.p[I_FC1];
    float f0 = fc1[j * 3], f1 = fc1[j * 3 + 1], f2 = fc1[j * 3 + 2];
    float hp = P.p[I_FC1B][j] + q0 * f0 + q1 * f1 + q2 * f2;
    float ss = sigf(hp);
    *(float4*)(urow + j * 4) = make_float4(spf(hp), ss * f0, ss * f1, ss * f2);
    V4q Va = vmat(P.p[I_FC2] + j * 32, urow, P.p[I_FC2B][j]);
    V4q V2 = sp4(Va);
    *(float4*)(urow + j * 4) = make_float4(V2.c[0], V2.c[1], V2.c[2], V2.c[3]);
    V4q Vb = vmat(P.p[I_FC3] + j * 32, urow, P.p[I_FC3B][j]);
    V4q V3 = sp4(Vb);
    float f4 = P.p[I_FC4][j];
    Vg0 = V3.c[1] * f4; Vg1 = V3.c[2] * f4; Vg2 = V3.c[3] * f4;
  }

  // ---- t0 = q@w_yu0 + b_y0 (uniform s_loads) ----
  const float* yu0 = P.p[I_WYU0];
  float t0v[3];
#pragma unroll
  for (int k = 0; k < 3; ++k)
    t0v[k] = q0 * yu0[k] + q1 * yu0[3 + k] + q2 * yu0[6 + k] + P.p[I_BY0][k];

  // ---- u1 = sp(q@w_h0 + b_h0) ----
  V4q u1;
  {
    const float* wh0 = P.p[I_WH0];
    float w0 = wh0[j], w1 = wh0[32 + j], w2 = wh0[64 + j];
    float h = P.p[I_BH0][j] + q0 * w0 + q1 * w1 + q2 * w2;
    float ss = sigf(h);
    u1.c[0] = spf(h); u1.c[1] = ss * w0; u1.c[2] = ss * w1; u1.c[3] = ss * w2;
  }

  // ---- z1 = sp( (y*t0)@w_y0 + q@w_u0 + b_0 ) ----
  V22 z;
  {
    const float* Wy = P.p[I_WY0];
    const float* Wu = P.p[I_WU0];
    float wy0 = Wy[j], wy1 = Wy[32 + j], wy2 = Wy[64 + j];
    float wu0 = Wu[j], wu1 = Wu[32 + j], wu2 = Wu[64 + j];
    V22 A;
    A.c[0] = P.p[I_B0][j] + (y0 * t0v[0]) * wy0 + (y1 * t0v[1]) * wy1 + (y2 * t0v[2]) * wy2 +
             q0 * wu0 + q1 * wu1 + q2 * wu2;
    A.c[1] = t0v[0] * wy0; A.c[2] = t0v[1] * wy1; A.c[3] = t0v[2] * wy2;
#pragma unroll
    for (int b = 0; b < 3; ++b) {
      float acc = (b == 0 ? wu0 : (b == 1 ? wu1 : wu2));
      acc += y0 * yu0[b * 3 + 0] * wy0 + y1 * yu0[b * 3 + 1] * wy1 + y2 * yu0[b * 3 + 2] * wy2;
      A.c[4 + b] = acc;
    }
#pragma unroll
    for (int t = 0; t < 6; ++t) A.c[7 + t] = 0.0f;
#pragma unroll
    for (int b = 0; b < 3; ++b) {
      A.c[13 + 0 * 3 + b] = yu0[b * 3 + 0] * wy0;
      A.c[13 + 1 * 3 + b] = yu0[b * 3 + 1] * wy1;
      A.c[13 + 2 * 3 + b] = yu0[b * 3 + 2] * wy2;
    }
    z = spchain22(A);
  }

  // ---- level 1 ----
  V4q u2;
  {
    *(float4*)(urow + j * 4) = make_float4(u1.c[0], u1.c[1], u1.c[2], u1.c[3]);
    V4q h1 = {{P.p[I_BH1][j], 0, 0, 0}}, s1 = {{P.p[I_BZ1][j], 0, 0, 0}};
    stageU_hs(P.p[I_WH1], P.p[I_WZU1], j, urow, h1, s1);
    u2 = sp4(h1);
    stageProd(prow + j * 28, z, s1);  // z,s1 -> LDS; z dead after this
    V4q w1 = {{P.p[I_B1][j], 0, 0, 0}};
    V4q t1a = {{P.p[I_BY1][0], 0, 0, 0}}, t1b = {{P.p[I_BY1][1], 0, 0, 0}},
        t1c = {{P.p[I_BY1][2], 0, 0, 0}};
    stageU_wt(P.p[I_WU1], P.p[I_WYU1], j, urow, w1, t1a, t1b, t1c);
    V22 A2;
    buildA(P.p[I_WY1], j, y0, y1, y2, w1, t1a, t1b, t1c, A2);
    mv22gA<true>(P.p[I_WZ1], j, prow, A2);
    mv22gB<true>(P.p[I_WZ1], j, prow, A2);
    z = spchain22(A2);  // z2
  }

  // ---- level 2 ----
  V4q u3;
  {
    *(float4*)(urow + j * 4) = make_float4(u2.c[0], u2.c[1], u2.c[2], u2.c[3]);
    V4q h2 = {{P.p[I_BH2][j], 0, 0, 0}}, s2 = {{P.p[I_BZ2][j], 0, 0, 0}};
    stageU_hs(P.p[I_WH2], P.p[I_WZU2], j, urow, h2, s2);
    u3 = sp4(h2);
    stageProd(prow + j * 28, z, s2);
    V4q w2 = {{P.p[I_B2][j], 0, 0, 0}};
    V4q t2a = {{P.p[I_BY2][0], 0, 0, 0}}, t2b = {{P.p[I_BY2][1], 0, 0, 0}},
        t2c = {{P.p[I_BY2][2], 0, 0, 0}};
    stageU_wt(P.p[I_WU2], P.p[I_WYU2], j, urow, w2, t2a, t2b, t2c);
    V22 A3;
    buildA(P.p[I_WY2], j, y0, y1, y2, w2, t2a, t2b, t2c, A3);
    mv22gA<true>(P.p[I_WZ2], j, prow, A3);
    mv22gB<true>(P.p[I_WZ2], j, prow, A3);
    z = spchain22(A3);  // z3
  }

  // ---- level 3 (output-stage pre-terms), split passes ----
  *(float4*)(urow + j * 4) = make_float4(u3.c[0], u3.c[1], u3.c[2], u3.c[3]);
  V4q s3 = {{P.p[I_BZO][j], 0, 0, 0}};
  {
    const float* Wzuo = P.p[I_WZUO];
#pragma unroll 4
    for (int i = 0; i < 32; ++i) {
      float4 u = *(const float4*)(urow + i * 4);
      float wz = Wzuo[i * 32 + j];
      s3.c[0] += u.x * wz; s3.c[1] += u.y * wz; s3.c[2] += u.z * wz; s3.c[3] += u.w * wz;
    }
  }
  V4q wo = {{0, 0, 0, 0}};
  V4q t3a = {{P.p[I_BYO][0], 0, 0, 0}}, t3b = {{P.p[I_BYO][1], 0, 0, 0}},
      t3c = {{P.p[I_BYO][2], 0, 0, 0}};
  {
    const float* Wuo = P.p[I_WUO];
    const float* Wyuo = P.p[I_WYUO];
#pragma unroll 4
    for (int i = 0; i < 32; ++i) {
      float4 u = *(const float4*)(urow + i * 4);
      float wu = Wuo[i];  // uniform -> s_load
      wo.c[0] += u.x * wu; wo.c[1] += u.y * wu; wo.c[2] += u.z * wu; wo.c[3] += u.w * wu;
      float wy0 = Wyuo[i * 3], wy1 = Wyuo[i * 3 + 1], wy2 = Wyuo[i * 3 + 2];
      t3a.c[0] += u.x * wy0; t3a.c[1] += u.y * wy0; t3a.c[2] += u.z * wy0; t3a.c[3] += u.w * wy0;
      t3b.c[0] += u.x * wy1; t3b.c[1] += u.y * wy1; t3b.c[2] += u.z * wy1; t3b.c[3] += u.w * wy1;
      t3c.c[0] += u.x * wy2; t3c.c[1] += u.y * wy2; t3c.c[2] += u.z * wy2; t3c.c[3] += u.w * wy2;
    }
  }

  // ---- p3 = z3*s3, reduce 25 comps over 32 lanes ----
  float red[25];
  {
    V22 p3 = prodZS(z, s3);
    float wz = fmaxf(P.p[I_WZO][j], 0.0f);  // relu(w_z_out)
#pragma unroll
    for (int k = 0; k < 22; ++k) red[k] = p3.c[k] * wz;
    red[22] = Vg0; red[23] = Vg1; red[24] = Vg2;
  }
#pragma unroll
  for (int m = 16; m >= 1; m >>= 1) {
#pragma unroll
    for (int k = 0; k < 25; ++k) red[k] += __shfl_xor(red[k], m, 32);
  }

  if (j == 0) {
    const float* Wyo = P.p[I_WYO];
    const float wyo0 = Wyo[0], wyo1 = Wyo[1], wyo2 = Wyo[2];
    float Av = red[0] + wo.c[0] + P.p[I_BOUT][0] + y0 * t3a.c[0] * wyo0 +
               y1 * t3b.c[0] * wyo1 + y2 * t3c.c[0] * wyo2;
    float Agy[3];
    Agy[0] = red[1] + t3a.c[0] * wyo0;
    Agy[1] = red[2] + t3b.c[0] * wyo1;
    Agy[2] = red[3] + t3c.c[0] * wyo2;
    float Agq[3];
#pragma unroll
    for (int b = 0; b < 3; ++b)
      Agq[b] = red[4 + b] + wo.c[1 + b] + y0 * t3a.c[1 + b] * wyo0 +
               y1 * t3b.c[1 + b] * wyo1 + y2 * t3c.c[1 + b] * wyo2;
    float s = sigf(Av), d = s * (1.0f - s);

    double Mm[3][3], Cm[3][3];
    const int pa[6] = {0, 0, 0, 1, 1, 2}, pb[6] = {0, 1, 2, 1, 2, 2};
#pragma unroll
    for (int t = 0; t < 6; ++t) {
      double m = (double)s * (double)red[7 + t] +
                 (double)d * (double)Agy[pa[t]] * (double)Agy[pb[t]];
      Mm[pa[t]][pb[t]] = m; Mm[pb[t]][pa[t]] = m;
    }
#pragma unroll
    for (int b = 0; b < 3; ++b) {
      float ah0 = red[13 + 0 * 3 + b] + t3a.c[1 + b] * wyo0;
      float ah1 = red[13 + 1 * 3 + b] + t3b.c[1 + b] * wyo1;
      float ah2 = red[13 + 2 * 3 + b] + t3c.c[1 + b] * wyo2;
      Cm[0][b] = (double)s * (double)ah0 + (double)d * (double)Agy[0] * (double)Agq[b];
      Cm[1][b] = (double)s * (double)ah1 + (double)d * (double)Agy[1] * (double)Agq[b];
      Cm[2][b] = (double)s * (double)ah2 + (double)d * (double)Agy[2] * (double)Agq[b];
    }
    const double yd0 = (double)y0, yd1 = (double)y1, yd2 = (double)y2;
    double rr[3];
#pragma unroll
    for (int i2 = 0; i2 < 3; ++i2) {
      double g = (double)s * (double)Agq[i2] - (double)red[22 + i2];
      rr[i2] = g - (yd0 * Cm[i2][0] + yd1 * Cm[i2][1] + yd2 * Cm[i2][2]);
    }
    double a = Mm[0][0], b_ = Mm[0][1], c_ = Mm[0][2], dd = Mm[1][1], e = Mm[1][2], f = Mm[2][2];
    double A00 = dd * f - e * e, A01 = c_ * e - b_ * f, A02 = b_ * e - c_ * dd;
    double A11 = a * f - c_ * c_, A12 = b_ * c_ - a * e, A22 = a * dd - b_ * b_;
    double det = a * A00 + b_ * A01 + c_ * A02;
    double idet = 1.0 / det;
    double d0 = (A00 * rr[0] + A01 * rr[1] + A02 * rr[2]) * idet;
    double d1 = (A01 * rr[0] + A11 * rr[1] + A12 * rr[2]) * idet;
    double d2 = (A02 * rr[0] + A12 * rr[1] + A22 * rr[2]) * idet;

    float* O = out + (size_t)sample * 6;
    O[0] = q0 + 0.001f * y0;
    O[1] = q1 + 0.001f * y1;
    O[2] = q2 + 0.001f * y2;
    O[3] = y0 + 0.001f * (float)d0;
    O[4] = y1 + 0.001f * (float)d1;
    O[5] = y2 + 0.001f * (float)d2;
  }
}

extern "C" void kernel_launch(void* const* d_in, const int* in_sizes, int n_in,
                              void* d_out, int out_size, void* d_ws, size_t ws_size,
                              hipStream_t stream) {
  (void)in_sizes; (void)n_in; (void)d_ws; (void)ws_size; (void)out_size;
  Ptrs P;
  for (int i = 0; i < 44; ++i) P.p[i] = (const float*)d_in[i];
  float* out = (float*)d_out;
  dim3 grid(B_TOTAL / 8), block(NTH);
  hipLaunchKernelGGL(lnn_step_kernel, grid, block, 0, stream, P, out);
}

// Round 5
// 193.323 us; speedup vs baseline: 2.7627x; 2.7627x over previous
//
#include <hip/hip_runtime.h>

#define NTH 256
#define B_TOTAL 32768

struct Ptrs { const float* p[44]; };

// input indices
enum : int {
  I_X = 0,
  I_WH0 = 1, I_WY0 = 2, I_WYU0 = 3, I_WU0 = 4,
  I_WH1 = 5, I_WZ1 = 6, I_WZU1 = 7, I_WY1 = 8, I_WYU1 = 9, I_WU1 = 10,
  I_WH2 = 11, I_WZ2 = 12, I_WZU2 = 13, I_WY2 = 14, I_WYU2 = 15, I_WU2 = 16,
  I_WZO = 17, I_WZUO = 18, I_WYO = 19, I_WYUO = 20, I_WUO = 21,
  I_BY0 = 22, I_BH0 = 23, I_B0 = 24, I_BH1 = 25, I_BY1 = 26, I_BZ1 = 27, I_B1 = 28,
  I_BH2 = 29, I_BZ2 = 30, I_BY2 = 31, I_B2 = 32, I_BZO = 33, I_BYO = 34, I_BOUT = 35,
  I_FC1 = 36, I_FC1B = 37, I_FC2 = 38, I_FC2B = 39, I_FC3 = 40, I_FC3B = 41,
  I_FC4 = 42, I_FC4B = 43
};

// jet: c[0]=v, c[1..3]=dy, c[4..6]=dq, c[7..12]=d2yy sym {00,01,02,11,12,22},
// c[13..21]=d2ydq [a*3+b]
struct V22 { float c[22]; };
struct V4q { float c[4]; };

__device__ __forceinline__ float spf(float x) {
  return fmaxf(x, 0.0f) + __logf(1.0f + __expf(-fabsf(x)));
}
__device__ __forceinline__ float sigf(float x) {
  return __fdividef(1.0f, 1.0f + __expf(-x));
}

__device__ __forceinline__ V22 spchain22(const V22& A) {
  V22 Z;
  float s = sigf(A.c[0]);
  float d = s * (1.0f - s);
  Z.c[0] = spf(A.c[0]);
#pragma unroll
  for (int a = 0; a < 3; ++a) Z.c[1 + a] = s * A.c[1 + a];
#pragma unroll
  for (int b = 0; b < 3; ++b) Z.c[4 + b] = s * A.c[4 + b];
  const int pa[6] = {0, 0, 0, 1, 1, 2}, pb[6] = {0, 1, 2, 1, 2, 2};
#pragma unroll
  for (int t = 0; t < 6; ++t)
    Z.c[7 + t] = s * A.c[7 + t] + d * A.c[1 + pa[t]] * A.c[1 + pb[t]];
#pragma unroll
  for (int a = 0; a < 3; ++a)
#pragma unroll
    for (int b = 0; b < 3; ++b)
      Z.c[13 + a * 3 + b] = s * A.c[13 + a * 3 + b] + d * A.c[1 + a] * A.c[4 + b];
  return Z;
}

__device__ __forceinline__ V4q sp4(const V4q& h) {
  V4q u;
  float ss = sigf(h.c[0]);
  u.c[0] = spf(h.c[0]);
  u.c[1] = ss * h.c[1];
  u.c[2] = ss * h.c[2];
  u.c[3] = ss * h.c[3];
  return u;
}

// fused: P = Z * S (product-rule jet), streamed straight to LDS row as float4s
__device__ __forceinline__ void stageProd(float* row, const V22& Z, const V4q& S) {
  float z0 = Z.c[0], s0 = S.c[0];
  *(float4*)(row + 0) = make_float4(z0 * s0, s0 * Z.c[1], s0 * Z.c[2], s0 * Z.c[3]);
  *(float4*)(row + 4) = make_float4(z0 * S.c[1] + s0 * Z.c[4],
                                    z0 * S.c[2] + s0 * Z.c[5],
                                    z0 * S.c[3] + s0 * Z.c[6],
                                    s0 * Z.c[7]);
  *(float4*)(row + 8)  = make_float4(s0 * Z.c[8], s0 * Z.c[9], s0 * Z.c[10], s0 * Z.c[11]);
  *(float4*)(row + 12) = make_float4(s0 * Z.c[12],
                                     s0 * Z.c[13] + Z.c[1] * S.c[1],
                                     s0 * Z.c[14] + Z.c[1] * S.c[2],
                                     s0 * Z.c[15] + Z.c[1] * S.c[3]);
  *(float4*)(row + 16) = make_float4(s0 * Z.c[16] + Z.c[2] * S.c[1],
                                     s0 * Z.c[17] + Z.c[2] * S.c[2],
                                     s0 * Z.c[18] + Z.c[2] * S.c[3],
                                     s0 * Z.c[19] + Z.c[3] * S.c[1]);
  *(float4*)(row + 20) = make_float4(s0 * Z.c[20] + Z.c[3] * S.c[2],
                                     s0 * Z.c[21] + Z.c[3] * S.c[3], 0.0f, 0.0f);
}

// full-register product (only used for the final reduction stage)
__device__ __forceinline__ V22 prodZS(const V22& Z, const V4q& S) {
  V22 P;
  P.c[0] = Z.c[0] * S.c[0];
#pragma unroll
  for (int a = 0; a < 3; ++a) P.c[1 + a] = S.c[0] * Z.c[1 + a];
#pragma unroll
  for (int b = 0; b < 3; ++b) P.c[4 + b] = Z.c[0] * S.c[1 + b] + S.c[0] * Z.c[4 + b];
#pragma unroll
  for (int t = 0; t < 6; ++t) P.c[7 + t] = S.c[0] * Z.c[7 + t];
#pragma unroll
  for (int a = 0; a < 3; ++a)
#pragma unroll
    for (int b = 0; b < 3; ++b)
      P.c[13 + a * 3 + b] = S.c[0] * Z.c[13 + a * 3 + b] + Z.c[1 + a] * S.c[1 + b];
  return P;
}

// half-jet matvec passes: acc.c[0..11] / acc.c[12..21] += sum_i p[i][k]*relu(W[i*32+j])
template <bool RELU>
__device__ __forceinline__ void mv22gA(const float* __restrict__ W, int j,
                                       const float* ps, V22& acc) {
#pragma unroll 2
  for (int i = 0; i < 32; ++i) {
    float w = W[i * 32 + j];
    if (RELU) w = fmaxf(w, 0.0f);
    const float* r = ps + i * 28;
    float4 r0 = *(const float4*)(r + 0);
    float4 r1 = *(const float4*)(r + 4);
    float4 r2 = *(const float4*)(r + 8);
    acc.c[0] += r0.x * w;  acc.c[1] += r0.y * w;  acc.c[2] += r0.z * w;  acc.c[3] += r0.w * w;
    acc.c[4] += r1.x * w;  acc.c[5] += r1.y * w;  acc.c[6] += r1.z * w;  acc.c[7] += r1.w * w;
    acc.c[8] += r2.x * w;  acc.c[9] += r2.y * w;  acc.c[10] += r2.z * w; acc.c[11] += r2.w * w;
  }
}
template <bool RELU>
__device__ __forceinline__ void mv22gB(const float* __restrict__ W, int j,
                                       const float* ps, V22& acc) {
#pragma unroll 2
  for (int i = 0; i < 32; ++i) {
    float w = W[i * 32 + j];
    if (RELU) w = fmaxf(w, 0.0f);
    const float* r = ps + i * 28;
    float4 r3 = *(const float4*)(r + 12);
    float4 r4 = *(const float4*)(r + 16);
    float4 r5 = *(const float4*)(r + 20);
    acc.c[12] += r3.x * w; acc.c[13] += r3.y * w; acc.c[14] += r3.z * w; acc.c[15] += r3.w * w;
    acc.c[16] += r4.x * w; acc.c[17] += r4.y * w; acc.c[18] += r4.z * w; acc.c[19] += r4.w * w;
    acc.c[20] += r5.x * w; acc.c[21] += r5.y * w;
  }
}

// u-consumers, split into low-pressure passes
__device__ __forceinline__ void stageU_hs(const float* __restrict__ Wh,
                                          const float* __restrict__ Wzu, int j,
                                          const float* us, V4q& h, V4q& s) {
#pragma unroll 2
  for (int i = 0; i < 32; ++i) {
    float4 u = *(const float4*)(us + i * 4);
    float wh = Wh[i * 32 + j], wz = Wzu[i * 32 + j];
    h.c[0] += u.x * wh; h.c[1] += u.y * wh; h.c[2] += u.z * wh; h.c[3] += u.w * wh;
    s.c[0] += u.x * wz; s.c[1] += u.y * wz; s.c[2] += u.z * wz; s.c[3] += u.w * wz;
  }
}
__device__ __forceinline__ void stageU_wt(const float* __restrict__ Wu,
                                          const float* __restrict__ Wyu, int j,
                                          const float* us, V4q& w,
                                          V4q& t0, V4q& t1, V4q& t2) {
#pragma unroll 2
  for (int i = 0; i < 32; ++i) {
    float4 u = *(const float4*)(us + i * 4);
    float wu = Wu[i * 32 + j];
    w.c[0] += u.x * wu; w.c[1] += u.y * wu; w.c[2] += u.z * wu; w.c[3] += u.w * wu;
    float wy0 = Wyu[i * 3 + 0], wy1 = Wyu[i * 3 + 1], wy2 = Wyu[i * 3 + 2];
    t0.c[0] += u.x * wy0; t0.c[1] += u.y * wy0; t0.c[2] += u.z * wy0; t0.c[3] += u.w * wy0;
    t1.c[0] += u.x * wy1; t1.c[1] += u.y * wy1; t1.c[2] += u.z * wy1; t1.c[3] += u.w * wy1;
    t2.c[0] += u.x * wy2; t2.c[1] += u.y * wy2; t2.c[2] += u.z * wy2; t2.c[3] += u.w * wy2;
  }
}

// local (non-matvec) terms of a pre-activation: A = w + (y*t)@Wy, Wy (3,32) global
__device__ __forceinline__ void buildA(const float* __restrict__ Wy, int j, float y0, float y1,
                                       float y2, const V4q& w, const V4q& t0, const V4q& t1,
                                       const V4q& t2, V22& A) {
  float wy0 = Wy[j], wy1 = Wy[32 + j], wy2 = Wy[64 + j];
  A.c[0] = w.c[0] + y0 * t0.c[0] * wy0 + y1 * t1.c[0] * wy1 + y2 * t2.c[0] * wy2;
  A.c[1] = t0.c[0] * wy0; A.c[2] = t1.c[0] * wy1; A.c[3] = t2.c[0] * wy2;
#pragma unroll
  for (int b = 0; b < 3; ++b)
    A.c[4 + b] = w.c[1 + b] + y0 * t0.c[1 + b] * wy0 + y1 * t1.c[1 + b] * wy1 +
                 y2 * t2.c[1 + b] * wy2;
#pragma unroll
  for (int t6 = 0; t6 < 6; ++t6) A.c[7 + t6] = 0.0f;
#pragma unroll
  for (int b = 0; b < 3; ++b) {
    A.c[13 + 0 * 3 + b] = t0.c[1 + b] * wy0;
    A.c[13 + 1 * 3 + b] = t1.c[1 + b] * wy1;
    A.c[13 + 2 * 3 + b] = t2.c[1 + b] * wy2;
  }
}

// out = bias + V @ Wrow; fully static indexing
__device__ __forceinline__ V4q vmat(const float* __restrict__ Wrow, const float* us, float bias) {
  V4q a = {{bias, 0.f, 0.f, 0.f}};
#pragma unroll 2
  for (int r = 0; r < 8; ++r) {
    float4 w4 = *(const float4*)(Wrow + r * 4);
    float4 u0 = *(const float4*)(us + (r * 4 + 0) * 4);
    float4 u1 = *(const float4*)(us + (r * 4 + 1) * 4);
    float4 u2 = *(const float4*)(us + (r * 4 + 2) * 4);
    float4 u3 = *(const float4*)(us + (r * 4 + 3) * 4);
    a.c[0] += u0.x * w4.x + u1.x * w4.y + u2.x * w4.z + u3.x * w4.w;
    a.c[1] += u0.y * w4.x + u1.y * w4.y + u2.y * w4.z + u3.y * w4.w;
    a.c[2] += u0.z * w4.x + u1.z * w4.y + u2.z * w4.z + u3.z * w4.w;
    a.c[3] += u0.w * w4.x + u1.w * w4.y + u2.w * w4.z + u3.w * w4.w;
  }
  return a;
}

__global__ __launch_bounds__(NTH, 4) void lnn_step_kernel(Ptrs P, float* __restrict__ out) {
  // LDS: jet staging only (32 KiB). Reads are same-row broadcasts (conflict-free).
  __shared__ float pstage[4][2][32][28];  // 28 KiB
  __shared__ float ustage[4][2][32][4];   // 4 KiB

  const int tid = threadIdx.x;
  const int j = tid & 31;
  const int half = (tid >> 5) & 1;
  const int wv = tid >> 6;
  const int sample = blockIdx.x * 8 + (tid >> 5);

  float* prow = &pstage[wv][half][0][0];
  float* urow = &ustage[wv][half][0][0];

  const float* X = P.p[I_X] + sample * 6;
  const float q0 = X[0], q1 = X[1], q2 = X[2];
  const float y0 = X[3], y1 = X[4], y2 = X[5];

  // ---------------- V chain first; keep only dV/dq ----------------
  float Vg0, Vg1, Vg2;
  {
    const float* fc1 = P.p[I_FC1];
    float f0 = fc1[j * 3], f1 = fc1[j * 3 + 1], f2 = fc1[j * 3 + 2];
    float hp = P.p[I_FC1B][j] + q0 * f0 + q1 * f1 + q2 * f2;
    float ss = sigf(hp);
    *(float4*)(urow + j * 4) = make_float4(spf(hp), ss * f0, ss * f1, ss * f2);
    V4q Va = vmat(P.p[I_FC2] + j * 32, urow, P.p[I_FC2B][j]);
    V4q V2 = sp4(Va);
    *(float4*)(urow + j * 4) = make_float4(V2.c[0], V2.c[1], V2.c[2], V2.c[3]);
    V4q Vb = vmat(P.p[I_FC3] + j * 32, urow, P.p[I_FC3B][j]);
    V4q V3 = sp4(Vb);
    float f4 = P.p[I_FC4][j];
    Vg0 = V3.c[1] * f4; Vg1 = V3.c[2] * f4; Vg2 = V3.c[3] * f4;
  }

  // ---- t0 = q@w_yu0 + b_y0 (uniform s_loads) ----
  const float* yu0 = P.p[I_WYU0];
  float t0v[3];
#pragma unroll
  for (int k = 0; k < 3; ++k)
    t0v[k] = q0 * yu0[k] + q1 * yu0[3 + k] + q2 * yu0[6 + k] + P.p[I_BY0][k];

  // ---- u1 = sp(q@w_h0 + b_h0) ----
  V4q u1;
  {
    const float* wh0 = P.p[I_WH0];
    float w0 = wh0[j], w1 = wh0[32 + j], w2 = wh0[64 + j];
    float h = P.p[I_BH0][j] + q0 * w0 + q1 * w1 + q2 * w2;
    float ss = sigf(h);
    u1.c[0] = spf(h); u1.c[1] = ss * w0; u1.c[2] = ss * w1; u1.c[3] = ss * w2;
  }

  // ---- z1 = sp( (y*t0)@w_y0 + q@w_u0 + b_0 ) ----
  V22 z;
  {
    const float* Wy = P.p[I_WY0];
    const float* Wu = P.p[I_WU0];
    float wy0 = Wy[j], wy1 = Wy[32 + j], wy2 = Wy[64 + j];
    float wu0 = Wu[j], wu1 = Wu[32 + j], wu2 = Wu[64 + j];
    V22 A;
    A.c[0] = P.p[I_B0][j] + (y0 * t0v[0]) * wy0 + (y1 * t0v[1]) * wy1 + (y2 * t0v[2]) * wy2 +
             q0 * wu0 + q1 * wu1 + q2 * wu2;
    A.c[1] = t0v[0] * wy0; A.c[2] = t0v[1] * wy1; A.c[3] = t0v[2] * wy2;
#pragma unroll
    for (int b = 0; b < 3; ++b) {
      float acc = (b == 0 ? wu0 : (b == 1 ? wu1 : wu2));
      acc += y0 * yu0[b * 3 + 0] * wy0 + y1 * yu0[b * 3 + 1] * wy1 + y2 * yu0[b * 3 + 2] * wy2;
      A.c[4 + b] = acc;
    }
#pragma unroll
    for (int t = 0; t < 6; ++t) A.c[7 + t] = 0.0f;
#pragma unroll
    for (int b = 0; b < 3; ++b) {
      A.c[13 + 0 * 3 + b] = yu0[b * 3 + 0] * wy0;
      A.c[13 + 1 * 3 + b] = yu0[b * 3 + 1] * wy1;
      A.c[13 + 2 * 3 + b] = yu0[b * 3 + 2] * wy2;
    }
    z = spchain22(A);
  }

  // ---- level 1 ----
  V4q u2;
  {
    *(float4*)(urow + j * 4) = make_float4(u1.c[0], u1.c[1], u1.c[2], u1.c[3]);
    V4q h1 = {{P.p[I_BH1][j], 0, 0, 0}}, s1 = {{P.p[I_BZ1][j], 0, 0, 0}};
    stageU_hs(P.p[I_WH1], P.p[I_WZU1], j, urow, h1, s1);
    u2 = sp4(h1);
    stageProd(prow + j * 28, z, s1);  // z,s1 -> LDS; z dead after this
    V4q w1 = {{P.p[I_B1][j], 0, 0, 0}};
    V4q t1a = {{P.p[I_BY1][0], 0, 0, 0}}, t1b = {{P.p[I_BY1][1], 0, 0, 0}},
        t1c = {{P.p[I_BY1][2], 0, 0, 0}};
    stageU_wt(P.p[I_WU1], P.p[I_WYU1], j, urow, w1, t1a, t1b, t1c);
    V22 A2;
    buildA(P.p[I_WY1], j, y0, y1, y2, w1, t1a, t1b, t1c, A2);
    mv22gA<true>(P.p[I_WZ1], j, prow, A2);
    mv22gB<true>(P.p[I_WZ1], j, prow, A2);
    z = spchain22(A2);  // z2
  }

  // ---- level 2 ----
  V4q u3;
  {
    *(float4*)(urow + j * 4) = make_float4(u2.c[0], u2.c[1], u2.c[2], u2.c[3]);
    V4q h2 = {{P.p[I_BH2][j], 0, 0, 0}}, s2 = {{P.p[I_BZ2][j], 0, 0, 0}};
    stageU_hs(P.p[I_WH2], P.p[I_WZU2], j, urow, h2, s2);
    u3 = sp4(h2);
    stageProd(prow + j * 28, z, s2);
    V4q w2 = {{P.p[I_B2][j], 0, 0, 0}};
    V4q t2a = {{P.p[I_BY2][0], 0, 0, 0}}, t2b = {{P.p[I_BY2][1], 0, 0, 0}},
        t2c = {{P.p[I_BY2][2], 0, 0, 0}};
    stageU_wt(P.p[I_WU2], P.p[I_WYU2], j, urow, w2, t2a, t2b, t2c);
    V22 A3;
    buildA(P.p[I_WY2], j, y0, y1, y2, w2, t2a, t2b, t2c, A3);
    mv22gA<true>(P.p[I_WZ2], j, prow, A3);
    mv22gB<true>(P.p[I_WZ2], j, prow, A3);
    z = spchain22(A3);  // z3
  }

  // ---- level 3 (output-stage pre-terms), split passes ----
  *(float4*)(urow + j * 4) = make_float4(u3.c[0], u3.c[1], u3.c[2], u3.c[3]);
  V4q s3 = {{P.p[I_BZO][j], 0, 0, 0}};
  {
    const float* Wzuo = P.p[I_WZUO];
#pragma unroll 2
    for (int i = 0; i < 32; ++i) {
      float4 u = *(const float4*)(urow + i * 4);
      float wz = Wzuo[i * 32 + j];
      s3.c[0] += u.x * wz; s3.c[1] += u.y * wz; s3.c[2] += u.z * wz; s3.c[3] += u.w * wz;
    }
  }
  V4q wo = {{0, 0, 0, 0}};
  V4q t3a = {{P.p[I_BYO][0], 0, 0, 0}}, t3b = {{P.p[I_BYO][1], 0, 0, 0}},
      t3c = {{P.p[I_BYO][2], 0, 0, 0}};
  {
    const float* Wuo = P.p[I_WUO];
    const float* Wyuo = P.p[I_WYUO];
#pragma unroll 2
    for (int i = 0; i < 32; ++i) {
      float4 u = *(const float4*)(urow + i * 4);
      float wu = Wuo[i];  // uniform -> s_load
      wo.c[0] += u.x * wu; wo.c[1] += u.y * wu; wo.c[2] += u.z * wu; wo.c[3] += u.w * wu;
      float wy0 = Wyuo[i * 3], wy1 = Wyuo[i * 3 + 1], wy2 = Wyuo[i * 3 + 2];
      t3a.c[0] += u.x * wy0; t3a.c[1] += u.y * wy0; t3a.c[2] += u.z * wy0; t3a.c[3] += u.w * wy0;
      t3b.c[0] += u.x * wy1; t3b.c[1] += u.y * wy1; t3b.c[2] += u.z * wy1; t3b.c[3] += u.w * wy1;
      t3c.c[0] += u.x * wy2; t3c.c[1] += u.y * wy2; t3c.c[2] += u.z * wy2; t3c.c[3] += u.w * wy2;
    }
  }

  // ---- p3 = z3*s3, reduce 25 comps over 32 lanes ----
  float red[25];
  {
    V22 p3 = prodZS(z, s3);
    float wz = fmaxf(P.p[I_WZO][j], 0.0f);  // relu(w_z_out)
#pragma unroll
    for (int k = 0; k < 22; ++k) red[k] = p3.c[k] * wz;
    red[22] = Vg0; red[23] = Vg1; red[24] = Vg2;
  }
#pragma unroll
  for (int m = 16; m >= 1; m >>= 1) {
#pragma unroll
    for (int k = 0; k < 25; ++k) red[k] += __shfl_xor(red[k], m, 32);
  }

  if (j == 0) {
    const float* Wyo = P.p[I_WYO];
    const float wyo0 = Wyo[0], wyo1 = Wyo[1], wyo2 = Wyo[2];
    float Av = red[0] + wo.c[0] + P.p[I_BOUT][0] + y0 * t3a.c[0] * wyo0 +
               y1 * t3b.c[0] * wyo1 + y2 * t3c.c[0] * wyo2;
    float Agy[3];
    Agy[0] = red[1] + t3a.c[0] * wyo0;
    Agy[1] = red[2] + t3b.c[0] * wyo1;
    Agy[2] = red[3] + t3c.c[0] * wyo2;
    float Agq[3];
#pragma unroll
    for (int b = 0; b < 3; ++b)
      Agq[b] = red[4 + b] + wo.c[1 + b] + y0 * t3a.c[1 + b] * wyo0 +
               y1 * t3b.c[1 + b] * wyo1 + y2 * t3c.c[1 + b] * wyo2;
    float s = sigf(Av), d = s * (1.0f - s);

    double Mm[3][3], Cm[3][3];
    const int pa[6] = {0, 0, 0, 1, 1, 2}, pb[6] = {0, 1, 2, 1, 2, 2};
#pragma unroll
    for (int t = 0; t < 6; ++t) {
      double m = (double)s * (double)red[7 + t] +
                 (double)d * (double)Agy[pa[t]] * (double)Agy[pb[t]];
      Mm[pa[t]][pb[t]] = m; Mm[pb[t]][pa[t]] = m;
    }
#pragma unroll
    for (int b = 0; b < 3; ++b) {
      float ah0 = red[13 + 0 * 3 + b] + t3a.c[1 + b] * wyo0;
      float ah1 = red[13 + 1 * 3 + b] + t3b.c[1 + b] * wyo1;
      float ah2 = red[13 + 2 * 3 + b] + t3c.c[1 + b] * wyo2;
      Cm[0][b] = (double)s * (double)ah0 + (double)d * (double)Agy[0] * (double)Agq[b];
      Cm[1][b] = (double)s * (double)ah1 + (double)d * (double)Agy[1] * (double)Agq[b];
      Cm[2][b] = (double)s * (double)ah2 + (double)d * (double)Agy[2] * (double)Agq[b];
    }
    const double yd0 = (double)y0, yd1 = (double)y1, yd2 = (double)y2;
    double rr[3];
#pragma unroll
    for (int i2 = 0; i2 < 3; ++i2) {
      double g = (double)s * (double)Agq[i2] - (double)red[22 + i2];
      rr[i2] = g - (yd0 * Cm[i2][0] + yd1 * Cm[i2][1] + yd2 * Cm[i2][2]);
    }
    double a = Mm[0][0], b_ = Mm[0][1], c_ = Mm[0][2], dd = Mm[1][1], e = Mm[1][2], f = Mm[2][2];
    double A00 = dd * f - e * e, A01 = c_ * e - b_ * f, A02 = b_ * e - c_ * dd;
    double A11 = a * f - c_ * c_, A12 = b_ * c_ - a * e, A22 = a * dd - b_ * b_;
    double det = a * A00 + b_ * A01 + c_ * A02;
    double idet = 1.0 / det;
    double d0 = (A00 * rr[0] + A01 * rr[1] + A02 * rr[2]) * idet;
    double d1 = (A01 * rr[0] + A11 * rr[1] + A12 * rr[2]) * idet;
    double d2 = (A02 * rr[0] + A12 * rr[1] + A22 * rr[2]) * idet;

    float* O = out + (size_t)sample * 6;
    O[0] = q0 + 0.001f * y0;
    O[1] = q1 + 0.001f * y1;
    O[2] = q2 + 0.001f * y2;
    O[3] = y0 + 0.001f * (float)d0;
    O[4] = y1 + 0.001f * (float)d1;
    O[5] = y2 + 0.001f * (float)d2;
  }
}

extern "C" void kernel_launch(void* const* d_in, const int* in_sizes, int n_in,
                              void* d_out, int out_size, void* d_ws, size_t ws_size,
                              hipStream_t stream) {
  (void)in_sizes; (void)n_in; (void)d_ws; (void)ws_size; (void)out_size;
  Ptrs P;
  for (int i = 0; i < 44; ++i) P.p[i] = (const float*)d_in[i];
  float* out = (float*)d_out;
  dim3 grid(B_TOTAL / 8), block(NTH);
  hipLaunchKernelGGL(lnn_step_kernel, grid, block, 0, stream, P, out);
}

// Round 6
// 161.486 us; speedup vs baseline: 3.3074x; 1.1972x over previous
//
#include <hip/hip_runtime.h>

#define NTH 256
#define B_TOTAL 32768

typedef float v2f __attribute__((ext_vector_type(2)));
typedef float v4f __attribute__((ext_vector_type(4)));

struct Ptrs { const float* p[44]; };

// input indices
enum : int {
  I_X = 0,
  I_WH0 = 1, I_WY0 = 2, I_WYU0 = 3, I_WU0 = 4,
  I_WH1 = 5, I_WZ1 = 6, I_WZU1 = 7, I_WY1 = 8, I_WYU1 = 9, I_WU1 = 10,
  I_WH2 = 11, I_WZ2 = 12, I_WZU2 = 13, I_WY2 = 14, I_WYU2 = 15, I_WU2 = 16,
  I_WZO = 17, I_WZUO = 18, I_WYO = 19, I_WYUO = 20, I_WUO = 21,
  I_BY0 = 22, I_BH0 = 23, I_B0 = 24, I_BH1 = 25, I_BY1 = 26, I_BZ1 = 27, I_B1 = 28,
  I_BH2 = 29, I_BZ2 = 30, I_BY2 = 31, I_B2 = 32, I_BZO = 33, I_BYO = 34, I_BOUT = 35,
  I_FC1 = 36, I_FC1B = 37, I_FC2 = 38, I_FC2B = 39, I_FC3 = 40, I_FC3B = 41,
  I_FC4 = 42, I_FC4B = 43
};

// jet: c[0]=v, c[1..3]=dy, c[4..6]=dq, c[7..12]=d2yy sym {00,01,02,11,12,22},
// c[13..21]=d2ydq [a*3+b]
struct V22 { float c[22]; };

__device__ __forceinline__ float spf(float x) {
  return fmaxf(x, 0.0f) + __logf(1.0f + __expf(-fabsf(x)));
}
__device__ __forceinline__ float sigf(float x) {
  return __fdividef(1.0f, 1.0f + __expf(-x));
}

__device__ __forceinline__ V22 spchain22(const V22& A) {
  V22 Z;
  float s = sigf(A.c[0]);
  float d = s * (1.0f - s);
  Z.c[0] = spf(A.c[0]);
#pragma unroll
  for (int a = 0; a < 3; ++a) Z.c[1 + a] = s * A.c[1 + a];
#pragma unroll
  for (int b = 0; b < 3; ++b) Z.c[4 + b] = s * A.c[4 + b];
  const int pa[6] = {0, 0, 0, 1, 1, 2}, pb[6] = {0, 1, 2, 1, 2, 2};
#pragma unroll
  for (int t = 0; t < 6; ++t)
    Z.c[7 + t] = s * A.c[7 + t] + d * A.c[1 + pa[t]] * A.c[1 + pb[t]];
#pragma unroll
  for (int a = 0; a < 3; ++a)
#pragma unroll
    for (int b = 0; b < 3; ++b)
      Z.c[13 + a * 3 + b] = s * A.c[13 + a * 3 + b] + d * A.c[1 + a] * A.c[4 + b];
  return Z;
}

// P = Z * S (product rule), streamed straight to LDS row (stride 24 floats, 16B-aligned)
__device__ __forceinline__ void stageProd(float* row, const V22& Z, float S0, float S1,
                                          float S2, float S3) {
  float z0 = Z.c[0];
  v4f w0 = {z0 * S0, S0 * Z.c[1], S0 * Z.c[2], S0 * Z.c[3]};
  v4f w1 = {z0 * S1 + S0 * Z.c[4], z0 * S2 + S0 * Z.c[5], z0 * S3 + S0 * Z.c[6], S0 * Z.c[7]};
  v4f w2 = {S0 * Z.c[8], S0 * Z.c[9], S0 * Z.c[10], S0 * Z.c[11]};
  v4f w3 = {S0 * Z.c[12], S0 * Z.c[13] + Z.c[1] * S1, S0 * Z.c[14] + Z.c[1] * S2,
            S0 * Z.c[15] + Z.c[1] * S3};
  v4f w4 = {S0 * Z.c[16] + Z.c[2] * S1, S0 * Z.c[17] + Z.c[2] * S2, S0 * Z.c[18] + Z.c[2] * S3,
            S0 * Z.c[19] + Z.c[3] * S1};
  v4f w5 = {S0 * Z.c[20] + Z.c[3] * S2, S0 * Z.c[21] + Z.c[3] * S3, 0.0f, 0.0f};
  *(v4f*)(row + 0) = w0;  *(v4f*)(row + 4) = w1;  *(v4f*)(row + 8) = w2;
  *(v4f*)(row + 12) = w3; *(v4f*)(row + 16) = w4; *(v4f*)(row + 20) = w5;
}

// full-register product (final reduction stage only)
__device__ __forceinline__ V22 prodZS(const V22& Z, float S0, float S1, float S2, float S3) {
  V22 P;
  const float Sq[3] = {S1, S2, S3};
  P.c[0] = Z.c[0] * S0;
#pragma unroll
  for (int a = 0; a < 3; ++a) P.c[1 + a] = S0 * Z.c[1 + a];
#pragma unroll
  for (int b = 0; b < 3; ++b) P.c[4 + b] = Z.c[0] * Sq[b] + S0 * Z.c[4 + b];
#pragma unroll
  for (int t = 0; t < 6; ++t) P.c[7 + t] = S0 * Z.c[7 + t];
#pragma unroll
  for (int a = 0; a < 3; ++a)
#pragma unroll
    for (int b = 0; b < 3; ++b)
      P.c[13 + a * 3 + b] = S0 * Z.c[13 + a * 3 + b] + Z.c[1 + a] * Sq[b];
  return P;
}

// packed half-jet matvec passes over relu(W): comps 0..11 and 12..21
__device__ __forceinline__ void mvA(const float* __restrict__ W, int j, const float* ps,
                                    v2f& m0, v2f& m1, v2f& m2, v2f& m3, v2f& m4, v2f& m5) {
#pragma unroll 2
  for (int i = 0; i < 32; ++i) {
    float w = fmaxf(W[i * 32 + j], 0.0f);
    const float* r = ps + i * 24;
    v4f r0 = *(const v4f*)(r + 0);
    v4f r1 = *(const v4f*)(r + 4);
    v4f r2 = *(const v4f*)(r + 8);
    m0 += r0.xy * w; m1 += r0.zw * w;
    m2 += r1.xy * w; m3 += r1.zw * w;
    m4 += r2.xy * w; m5 += r2.zw * w;
  }
}
__device__ __forceinline__ void mvB(const float* __restrict__ W, int j, const float* ps,
                                    v2f& m6, v2f& m7, v2f& m8, v2f& m9, v2f& m10) {
#pragma unroll 2
  for (int i = 0; i < 32; ++i) {
    float w = fmaxf(W[i * 32 + j], 0.0f);
    const float* r = ps + i * 24;
    v4f r3 = *(const v4f*)(r + 12);
    v4f r4 = *(const v4f*)(r + 16);
    v2f r5 = *(const v2f*)(r + 20);
    m6 += r3.xy * w; m7 += r3.zw * w;
    m8 += r4.xy * w; m9 += r4.zw * w;
    m10 += r5 * w;
  }
}

// packed u-consumers
__device__ __forceinline__ void stageU_hs(const float* __restrict__ Wh,
                                          const float* __restrict__ Wzu, int j,
                                          const float* us, v2f& h0, v2f& h1, v2f& s0, v2f& s1) {
#pragma unroll 2
  for (int i = 0; i < 32; ++i) {
    v4f u = *(const v4f*)(us + i * 4);
    float wh = Wh[i * 32 + j], wz = Wzu[i * 32 + j];
    h0 += u.xy * wh; h1 += u.zw * wh;
    s0 += u.xy * wz; s1 += u.zw * wz;
  }
}
__device__ __forceinline__ void stageU_wt(const float* __restrict__ Wu,
                                          const float* __restrict__ Wyu, int j,
                                          const float* us, v2f& w0, v2f& w1,
                                          v2f& ta0, v2f& ta1, v2f& tb0, v2f& tb1,
                                          v2f& tc0, v2f& tc1) {
#pragma unroll 2
  for (int i = 0; i < 32; ++i) {
    v4f u = *(const v4f*)(us + i * 4);
    float wu = Wu[i * 32 + j];
    w0 += u.xy * wu; w1 += u.zw * wu;
    float wy0 = Wyu[i * 3 + 0], wy1 = Wyu[i * 3 + 1], wy2 = Wyu[i * 3 + 2];
    ta0 += u.xy * wy0; ta1 += u.zw * wy0;
    tb0 += u.xy * wy1; tb1 += u.zw * wy1;
    tc0 += u.xy * wy2; tc1 += u.zw * wy2;
  }
}

// local (non-matvec) pre-activation terms: A = w + (y*t)@Wy, Wy (3,32)
__device__ __forceinline__ void buildA(const float* __restrict__ Wy, int j, float y0, float y1,
                                       float y2, const float wv[4], const float ta[4],
                                       const float tb[4], const float tc[4], V22& A) {
  float wy0 = Wy[j], wy1 = Wy[32 + j], wy2 = Wy[64 + j];
  A.c[0] = wv[0] + y0 * ta[0] * wy0 + y1 * tb[0] * wy1 + y2 * tc[0] * wy2;
  A.c[1] = ta[0] * wy0; A.c[2] = tb[0] * wy1; A.c[3] = tc[0] * wy2;
#pragma unroll
  for (int b = 0; b < 3; ++b)
    A.c[4 + b] = wv[1 + b] + y0 * ta[1 + b] * wy0 + y1 * tb[1 + b] * wy1 + y2 * tc[1 + b] * wy2;
#pragma unroll
  for (int t6 = 0; t6 < 6; ++t6) A.c[7 + t6] = 0.0f;
#pragma unroll
  for (int b = 0; b < 3; ++b) {
    A.c[13 + 0 * 3 + b] = ta[1 + b] * wy0;
    A.c[13 + 1 * 3 + b] = tb[1 + b] * wy1;
    A.c[13 + 2 * 3 + b] = tc[1 + b] * wy2;
  }
}

__global__ __launch_bounds__(NTH, 4) void lnn_step_kernel(Ptrs P, float* __restrict__ out) {
  // LDS: jet staging only (28 KiB). Row stride 24 floats (96B, 16B-aligned).
  // Reads are same-row broadcasts (conflict-free; 2-way half-wave alias is free).
  __shared__ float pstage[4][2][32][24];  // 24 KiB
  __shared__ float ustage[4][2][32][4];   // 4 KiB

  const int tid = threadIdx.x;
  const int j = tid & 31;
  const int half = (tid >> 5) & 1;
  const int wv = tid >> 6;
  const int sample = blockIdx.x * 8 + (tid >> 5);

  float* prow = &pstage[wv][half][0][0];
  float* urow = &ustage[wv][half][0][0];

  const float* X = P.p[I_X] + sample * 6;
  const float q0 = X[0], q1 = X[1], q2 = X[2];
  const float y0 = X[3], y1 = X[4], y2 = X[5];

  // ---------------- V chain first; keep only dV/dq ----------------
  float Vg0, Vg1, Vg2;
  {
    const float* fc1 = P.p[I_FC1];
    float f0 = fc1[j * 3], f1 = fc1[j * 3 + 1], f2 = fc1[j * 3 + 2];
    float hp = P.p[I_FC1B][j] + q0 * f0 + q1 * f1 + q2 * f2;
    float ss = sigf(hp);
    v4f V1 = {spf(hp), ss * f0, ss * f1, ss * f2};
    *(v4f*)(urow + j * 4) = V1;
    const float* fc2 = P.p[I_FC2] + j * 32;
    v2f a0 = {P.p[I_FC2B][j], 0.0f}, a1 = {0.0f, 0.0f};
#pragma unroll 2
    for (int r = 0; r < 8; ++r) {
      v4f w4 = *(const v4f*)(fc2 + r * 4);
      v4f u0 = *(const v4f*)(urow + (r * 4 + 0) * 4);
      v4f u1 = *(const v4f*)(urow + (r * 4 + 1) * 4);
      v4f u2 = *(const v4f*)(urow + (r * 4 + 2) * 4);
      v4f u3 = *(const v4f*)(urow + (r * 4 + 3) * 4);
      a0 += u0.xy * w4.x; a1 += u0.zw * w4.x;
      a0 += u1.xy * w4.y; a1 += u1.zw * w4.y;
      a0 += u2.xy * w4.z; a1 += u2.zw * w4.z;
      a0 += u3.xy * w4.w; a1 += u3.zw * w4.w;
    }
    float ss2 = sigf(a0.x);
    v4f V2 = {spf(a0.x), ss2 * a0.y, ss2 * a1.x, ss2 * a1.y};
    *(v4f*)(urow + j * 4) = V2;
    const float* fc3 = P.p[I_FC3] + j * 32;
    v2f b0 = {P.p[I_FC3B][j], 0.0f}, b1 = {0.0f, 0.0f};
#pragma unroll 2
    for (int r = 0; r < 8; ++r) {
      v4f w4 = *(const v4f*)(fc3 + r * 4);
      v4f u0 = *(const v4f*)(urow + (r * 4 + 0) * 4);
      v4f u1 = *(const v4f*)(urow + (r * 4 + 1) * 4);
      v4f u2 = *(const v4f*)(urow + (r * 4 + 2) * 4);
      v4f u3 = *(const v4f*)(urow + (r * 4 + 3) * 4);
      b0 += u0.xy * w4.x; b1 += u0.zw * w4.x;
      b0 += u1.xy * w4.y; b1 += u1.zw * w4.y;
      b0 += u2.xy * w4.z; b1 += u2.zw * w4.z;
      b0 += u3.xy * w4.w; b1 += u3.zw * w4.w;
    }
    float ss3 = sigf(b0.x);
    float f4 = P.p[I_FC4][j];
    Vg0 = ss3 * b0.y * f4; Vg1 = ss3 * b1.x * f4; Vg2 = ss3 * b1.y * f4;
  }

  // ---- t0 = q@w_yu0 + b_y0 (uniform s_loads) ----
  const float* yu0 = P.p[I_WYU0];
  float t0v[3];
#pragma unroll
  for (int k = 0; k < 3; ++k)
    t0v[k] = q0 * yu0[k] + q1 * yu0[3 + k] + q2 * yu0[6 + k] + P.p[I_BY0][k];

  // ---- u1 = sp(q@w_h0 + b_h0) ----
  float u1c[4];
  {
    const float* wh0 = P.p[I_WH0];
    float w0 = wh0[j], w1 = wh0[32 + j], w2 = wh0[64 + j];
    float h = P.p[I_BH0][j] + q0 * w0 + q1 * w1 + q2 * w2;
    float ss = sigf(h);
    u1c[0] = spf(h); u1c[1] = ss * w0; u1c[2] = ss * w1; u1c[3] = ss * w2;
  }

  // ---- z1 = sp( (y*t0)@w_y0 + q@w_u0 + b_0 ) ----
  V22 z;
  {
    const float* Wy = P.p[I_WY0];
    const float* Wu = P.p[I_WU0];
    float wy0 = Wy[j], wy1 = Wy[32 + j], wy2 = Wy[64 + j];
    float wu0 = Wu[j], wu1 = Wu[32 + j], wu2 = Wu[64 + j];
    V22 A;
    A.c[0] = P.p[I_B0][j] + (y0 * t0v[0]) * wy0 + (y1 * t0v[1]) * wy1 + (y2 * t0v[2]) * wy2 +
             q0 * wu0 + q1 * wu1 + q2 * wu2;
    A.c[1] = t0v[0] * wy0; A.c[2] = t0v[1] * wy1; A.c[3] = t0v[2] * wy2;
#pragma unroll
    for (int b = 0; b < 3; ++b) {
      float acc = (b == 0 ? wu0 : (b == 1 ? wu1 : wu2));
      acc += y0 * yu0[b * 3 + 0] * wy0 + y1 * yu0[b * 3 + 1] * wy1 + y2 * yu0[b * 3 + 2] * wy2;
      A.c[4 + b] = acc;
    }
#pragma unroll
    for (int t = 0; t < 6; ++t) A.c[7 + t] = 0.0f;
#pragma unroll
    for (int b = 0; b < 3; ++b) {
      A.c[13 + 0 * 3 + b] = yu0[b * 3 + 0] * wy0;
      A.c[13 + 1 * 3 + b] = yu0[b * 3 + 1] * wy1;
      A.c[13 + 2 * 3 + b] = yu0[b * 3 + 2] * wy2;
    }
    z = spchain22(A);
  }

  // ---- levels 1 and 2 ----
  float unext[4];
#pragma unroll 1
  for (int lvl = 0; lvl < 2; ++lvl) {
    const float* Wh  = P.p[lvl == 0 ? I_WH1 : I_WH2];
    const float* Wzu = P.p[lvl == 0 ? I_WZU1 : I_WZU2];
    const float* Wu  = P.p[lvl == 0 ? I_WU1 : I_WU2];
    const float* Wyu = P.p[lvl == 0 ? I_WYU1 : I_WYU2];
    const float* Wy  = P.p[lvl == 0 ? I_WY1 : I_WY2];
    const float* Wz  = P.p[lvl == 0 ? I_WZ1 : I_WZ2];
    const float* Bh  = P.p[lvl == 0 ? I_BH1 : I_BH2];
    const float* Bz  = P.p[lvl == 0 ? I_BZ1 : I_BZ2];
    const float* Bl  = P.p[lvl == 0 ? I_B1 : I_B2];
    const float* By  = P.p[lvl == 0 ? I_BY1 : I_BY2];

    const float* uc = (lvl == 0) ? u1c : unext;
    v4f uu = {uc[0], uc[1], uc[2], uc[3]};
    *(v4f*)(urow + j * 4) = uu;

    v2f h0 = {Bh[j], 0.0f}, h1 = {0.0f, 0.0f};
    v2f s0 = {Bz[j], 0.0f}, s1 = {0.0f, 0.0f};
    stageU_hs(Wh, Wzu, j, urow, h0, h1, s0, s1);
    {
      float ss = sigf(h0.x);
      unext[0] = spf(h0.x); unext[1] = ss * h0.y; unext[2] = ss * h1.x; unext[3] = ss * h1.y;
    }
    stageProd(prow + j * 24, z, s0.x, s0.y, s1.x, s1.y);

    v2f w0 = {Bl[j], 0.0f}, w1 = {0.0f, 0.0f};
    v2f ta0 = {By[0], 0.0f}, ta1 = {0.0f, 0.0f};
    v2f tb0 = {By[1], 0.0f}, tb1 = {0.0f, 0.0f};
    v2f tc0 = {By[2], 0.0f}, tc1 = {0.0f, 0.0f};
    stageU_wt(Wu, Wyu, j, urow, w0, w1, ta0, ta1, tb0, tb1, tc0, tc1);

    float wvv[4] = {w0.x, w0.y, w1.x, w1.y};
    float tav[4] = {ta0.x, ta0.y, ta1.x, ta1.y};
    float tbv[4] = {tb0.x, tb0.y, tb1.x, tb1.y};
    float tcv[4] = {tc0.x, tc0.y, tc1.x, tc1.y};
    V22 A2;
    buildA(Wy, j, y0, y1, y2, wvv, tav, tbv, tcv, A2);

    v2f m0 = {A2.c[0], A2.c[1]},  m1 = {A2.c[2], A2.c[3]},  m2 = {A2.c[4], A2.c[5]};
    v2f m3 = {A2.c[6], A2.c[7]},  m4 = {A2.c[8], A2.c[9]},  m5 = {A2.c[10], A2.c[11]};
    v2f m6 = {A2.c[12], A2.c[13]}, m7 = {A2.c[14], A2.c[15]}, m8 = {A2.c[16], A2.c[17]};
    v2f m9 = {A2.c[18], A2.c[19]}, m10 = {A2.c[20], A2.c[21]};
    mvA(Wz, j, prow, m0, m1, m2, m3, m4, m5);
    mvB(Wz, j, prow, m6, m7, m8, m9, m10);
    A2.c[0] = m0.x;  A2.c[1] = m0.y;  A2.c[2] = m1.x;  A2.c[3] = m1.y;
    A2.c[4] = m2.x;  A2.c[5] = m2.y;  A2.c[6] = m3.x;  A2.c[7] = m3.y;
    A2.c[8] = m4.x;  A2.c[9] = m4.y;  A2.c[10] = m5.x; A2.c[11] = m5.y;
    A2.c[12] = m6.x; A2.c[13] = m6.y; A2.c[14] = m7.x; A2.c[15] = m7.y;
    A2.c[16] = m8.x; A2.c[17] = m8.y; A2.c[18] = m9.x; A2.c[19] = m9.y;
    A2.c[20] = m10.x; A2.c[21] = m10.y;
    z = spchain22(A2);
  }

  // ---- level 3 (output-stage pre-terms) ----
  {
    v4f uu = {unext[0], unext[1], unext[2], unext[3]};
    *(v4f*)(urow + j * 4) = uu;
  }
  v2f s30 = {P.p[I_BZO][j], 0.0f}, s31 = {0.0f, 0.0f};
  {
    const float* Wzuo = P.p[I_WZUO];
#pragma unroll 2
    for (int i = 0; i < 32; ++i) {
      v4f u = *(const v4f*)(urow + i * 4);
      float wz = Wzuo[i * 32 + j];
      s30 += u.xy * wz; s31 += u.zw * wz;
    }
  }
  v2f wo0 = {0.0f, 0.0f}, wo1 = {0.0f, 0.0f};
  v2f t3a0 = {P.p[I_BYO][0], 0.0f}, t3a1 = {0.0f, 0.0f};
  v2f t3b0 = {P.p[I_BYO][1], 0.0f}, t3b1 = {0.0f, 0.0f};
  v2f t3c0 = {P.p[I_BYO][2], 0.0f}, t3c1 = {0.0f, 0.0f};
  {
    const float* Wuo = P.p[I_WUO];
    const float* Wyuo = P.p[I_WYUO];
#pragma unroll 2
    for (int i = 0; i < 32; ++i) {
      v4f u = *(const v4f*)(urow + i * 4);
      float wu = Wuo[i];  // uniform -> s_load
      wo0 += u.xy * wu; wo1 += u.zw * wu;
      float wy0 = Wyuo[i * 3], wy1 = Wyuo[i * 3 + 1], wy2 = Wyuo[i * 3 + 2];
      t3a0 += u.xy * wy0; t3a1 += u.zw * wy0;
      t3b0 += u.xy * wy1; t3b1 += u.zw * wy1;
      t3c0 += u.xy * wy2; t3c1 += u.zw * wy2;
    }
  }
  const float woc[4] = {wo0.x, wo0.y, wo1.x, wo1.y};
  const float t3av[4] = {t3a0.x, t3a0.y, t3a1.x, t3a1.y};
  const float t3bv[4] = {t3b0.x, t3b0.y, t3b1.x, t3b1.y};
  const float t3cv[4] = {t3c0.x, t3c0.y, t3c1.x, t3c1.y};

  // ---- p3 = z3*s3, reduce 25 comps over 32 lanes ----
  float red[25];
  {
    V22 p3 = prodZS(z, s30.x, s30.y, s31.x, s31.y);
    float wz = fmaxf(P.p[I_WZO][j], 0.0f);  // relu(w_z_out)
#pragma unroll
    for (int k = 0; k < 22; ++k) red[k] = p3.c[k] * wz;
    red[22] = Vg0; red[23] = Vg1; red[24] = Vg2;
  }
#pragma unroll
  for (int m = 16; m >= 1; m >>= 1) {
#pragma unroll
    for (int k = 0; k < 25; ++k) red[k] += __shfl_xor(red[k], m, 32);
  }

  if (j == 0) {
    const float* Wyo = P.p[I_WYO];
    const float wyo0 = Wyo[0], wyo1 = Wyo[1], wyo2 = Wyo[2];
    float Av = red[0] + woc[0] + P.p[I_BOUT][0] + y0 * t3av[0] * wyo0 +
               y1 * t3bv[0] * wyo1 + y2 * t3cv[0] * wyo2;
    float Agy[3];
    Agy[0] = red[1] + t3av[0] * wyo0;
    Agy[1] = red[2] + t3bv[0] * wyo1;
    Agy[2] = red[3] + t3cv[0] * wyo2;
    float Agq[3];
#pragma unroll
    for (int b = 0; b < 3; ++b)
      Agq[b] = red[4 + b] + woc[1 + b] + y0 * t3av[1 + b] * wyo0 +
               y1 * t3bv[1 + b] * wyo1 + y2 * t3cv[1 + b] * wyo2;
    float s = sigf(Av), d = s * (1.0f - s);

    double Mm[3][3], Cm[3][3];
    const int pa[6] = {0, 0, 0, 1, 1, 2}, pb[6] = {0, 1, 2, 1, 2, 2};
#pragma unroll
    for (int t = 0; t < 6; ++t) {
      double m = (double)s * (double)red[7 + t] +
                 (double)d * (double)Agy[pa[t]] * (double)Agy[pb[t]];
      Mm[pa[t]][pb[t]] = m; Mm[pb[t]][pa[t]] = m;
    }
#pragma unroll
    for (int b = 0; b < 3; ++b) {
      float ah0 = red[13 + 0 * 3 + b] + t3av[1 + b] * wyo0;
      float ah1 = red[13 + 1 * 3 + b] + t3bv[1 + b] * wyo1;
      float ah2 = red[13 + 2 * 3 + b] + t3cv[1 + b] * wyo2;
      Cm[0][b] = (double)s * (double)ah0 + (double)d * (double)Agy[0] * (double)Agq[b];
      Cm[1][b] = (double)s * (double)ah1 + (double)d * (double)Agy[1] * (double)Agq[b];
      Cm[2][b] = (double)s * (double)ah2 + (double)d * (double)Agy[2] * (double)Agq[b];
    }
    const double yd0 = (double)y0, yd1 = (double)y1, yd2 = (double)y2;
    double rr[3];
#pragma unroll
    for (int i2 = 0; i2 < 3; ++i2) {
      double g = (double)s * (double)Agq[i2] - (double)red[22 + i2];
      rr[i2] = g - (yd0 * Cm[i2][0] + yd1 * Cm[i2][1] + yd2 * Cm[i2][2]);
    }
    double a = Mm[0][0], b_ = Mm[0][1], c_ = Mm[0][2], dd = Mm[1][1], e = Mm[1][2], f = Mm[2][2];
    double A00 = dd * f - e * e, A01 = c_ * e - b_ * f, A02 = b_ * e - c_ * dd;
    double A11 = a * f - c_ * c_, A12 = b_ * c_ - a * e, A22 = a * dd - b_ * b_;
    double det = a * A00 + b_ * A01 + c_ * A02;
    double idet = 1.0 / det;
    double d0 = (A00 * rr[0] + A01 * rr[1] + A02 * rr[2]) * idet;
    double d1 = (A01 * rr[0] + A11 * rr[1] + A12 * rr[2]) * idet;
    double d2 = (A02 * rr[0] + A12 * rr[1] + A22 * rr[2]) * idet;

    float* O = out + (size_t)sample * 6;
    O[0] = q0 + 0.001f * y0;
    O[1] = q1 + 0.001f * y1;
    O[2] = q2 + 0.001f * y2;
    O[3] = y0 + 0.001f * (float)d0;
    O[4] = y1 + 0.001f * (float)d1;
    O[5] = y2 + 0.001f * (float)d2;
  }
}

extern "C" void kernel_launch(void* const* d_in, const int* in_sizes, int n_in,
                              void* d_out, int out_size, void* d_ws, size_t ws_size,
                              hipStream_t stream) {
  (void)in_sizes; (void)n_in; (void)d_ws; (void)ws_size; (void)out_size;
  Ptrs P;
  for (int i = 0; i < 44; ++i) P.p[i] = (const float*)d_in[i];
  float* out = (float*)d_out;
  dim3 grid(B_TOTAL / 8), block(NTH);
  hipLaunchKernelGGL(lnn_step_kernel, grid, block, 0, stream, P, out);
}